// Round 4
// baseline (103.845 us; speedup 1.0000x reference)
//
#include <hip/hip_runtime.h>
#include <hip/hip_fp16.h>
#include <hip/hip_bf16.h>

#define NB 256
#define IN_F 1024
#define BEX 256
#define KD 16
#define NJ 4096
#define OUT_F 1280

typedef short bf16x8 __attribute__((ext_vector_type(8)));
typedef float f32x4 __attribute__((ext_vector_type(4)));
typedef _Float16 h2 __attribute__((ext_vector_type(2)));

__device__ inline unsigned short f2bf(float f) {
    __hip_bfloat16 h = __float2bfloat16(f);
    return *reinterpret_cast<unsigned short*>(&h);
}

__device__ inline void cp16(const void* g, void* l) {
    __builtin_amdgcn_global_load_lds((const __attribute__((address_space(1))) void*)g,
                                     (__attribute__((address_space(3))) void*)l, 16, 0, 0);
}

// ---- kernel 1: prep ----
// blocks [0, 4096): transpose 32x32 tile of T (1024x4096 f32) -> Tt (4096x1024 bf16)
// blocks [4096, 4352): row r: out[r,:1024]=x[r]; out[r,1024:]=-1
__global__ __launch_bounds__(256) void k_prep(const float* __restrict__ x,
                                              const float* __restrict__ T,
                                              float* __restrict__ out,
                                              unsigned short* __restrict__ Tt) {
    const int bid = blockIdx.x;
    const int t = threadIdx.x;
    if (bid < 4096) {
        __shared__ float tile[32][33];
        const int j0 = (bid & 127) * 32;
        const int i0 = (bid >> 7) * 32;
        {
            const int r = t >> 3, cg = (t & 7) << 2;
            float4 v = *(const float4*)(T + (size_t)(i0 + r) * NJ + j0 + cg);
            tile[r][cg + 0] = v.x; tile[r][cg + 1] = v.y;
            tile[r][cg + 2] = v.z; tile[r][cg + 3] = v.w;
        }
        __syncthreads();
        const int jr = t >> 3, ig = (t & 7) << 2;
        ushort4 o;
        o.x = f2bf(tile[ig + 0][jr]);
        o.y = f2bf(tile[ig + 1][jr]);
        o.z = f2bf(tile[ig + 2][jr]);
        o.w = f2bf(tile[ig + 3][jr]);
        *(ushort4*)(Tt + (size_t)(j0 + jr) * IN_F + i0 + ig) = o;
    } else {
        const int r = bid - 4096;
        float4 v = *(const float4*)(x + (size_t)r * IN_F + t * 4);
        *(float4*)(out + (size_t)r * OUT_F + t * 4) = v;
        if (t < 64)
            *(float4*)(out + (size_t)r * OUT_F + IN_F + t * 4) =
                make_float4(-1.f, -1.f, -1.f, -1.f);
    }
}

// ---- kernel 2: bf16 MFMA GEMM, A staged from fp32 x (in-register cvt), B via DMA ----
// 64x64 tile, 4 waves (2x2 of 32x32), BK=128, both LDS operand sets double-buffered.
__global__ __launch_bounds__(256) void k_gemm(const float* __restrict__ X,            // [256][1024] f32
                                              const unsigned short* __restrict__ B,   // [4096][1024] bf16
                                              __half* __restrict__ M2h) {
    __shared__ unsigned short Abuf[2][64 * 128];   // 32 KB
    __shared__ unsigned short Bbuf[2][64 * 128];   // 32 KB
    const int t = threadIdx.x;
    const int w = t >> 6, l = t & 63;
    const int n0 = blockIdx.y * 64;
    const int j0 = blockIdx.x * 64;

    // ---- A staging map: thread t covers row r = t>>2, kg groups (t&3)*4 + p, p=0..3 ----
    const int ar = t >> 2;
    const int akg0 = (t & 3) * 4;
    const float* Aptr = X + (size_t)(n0 + ar) * IN_F + akg0 * 8;   // 32 consecutive k
    int aofs[4];
    #pragma unroll
    for (int p = 0; p < 4; ++p)
        aofs[p] = ar * 128 + (((akg0 + p) ^ (ar & 15)) * 8);

    // ---- B DMA map: slot s = t + p*256; row s>>4, kg (s&15)^(row&15) ----
    const unsigned short* aB[4];
    int bofs[4];
    #pragma unroll
    for (int p = 0; p < 4; ++p) {
        int s = t + p * 256;
        int r = s >> 4;
        int kg = (s & 15) ^ (r & 15);
        aB[p] = B + (size_t)(j0 + r) * IN_F + kg * 8;
        bofs[p] = s * 8;
    }

    f32x4 acc[2][2];
    #pragma unroll
    for (int i = 0; i < 2; ++i)
        #pragma unroll
        for (int j = 0; j < 2; ++j)
            acc[i][j] = (f32x4){0.f, 0.f, 0.f, 0.f};

    // prefetch chunk 0: A -> regs, B -> LDS (DMA)
    float4 apre[4][2];
    #pragma unroll
    for (int p = 0; p < 4; ++p) {
        apre[p][0] = *(const float4*)(Aptr + p * 8);
        apre[p][1] = *(const float4*)(Aptr + p * 8 + 4);
    }
    #pragma unroll
    for (int p = 0; p < 4; ++p) cp16(aB[p], &Bbuf[0][bofs[p]]);

    const int rowA0 = ((w & 1) * 32 + (l & 15)) * 128;
    const int rowA1 = rowA0 + 16 * 128;
    const int rowB0 = (((w >> 1) & 1) * 32 + (l & 15)) * 128;
    const int rowB1 = rowB0 + 16 * 128;

    for (int s = 0; s < 8; ++s) {
        // convert + write A(s) to LDS
        #pragma unroll
        for (int p = 0; p < 4; ++p) {
            union { bf16x8 v; unsigned short u[8]; } pk;
            pk.u[0] = f2bf(apre[p][0].x); pk.u[1] = f2bf(apre[p][0].y);
            pk.u[2] = f2bf(apre[p][0].z); pk.u[3] = f2bf(apre[p][0].w);
            pk.u[4] = f2bf(apre[p][1].x); pk.u[5] = f2bf(apre[p][1].y);
            pk.u[6] = f2bf(apre[p][1].z); pk.u[7] = f2bf(apre[p][1].w);
            *(bf16x8*)&Abuf[s & 1][aofs[p]] = pk.v;
        }
        __syncthreads();   // publishes A(s) stores + drains B(s) DMA

        // issue prefetch for chunk s+1
        if (s < 7) {
            const int k0 = (s + 1) * 128;
            #pragma unroll
            for (int p = 0; p < 4; ++p) {
                apre[p][0] = *(const float4*)(Aptr + k0 + p * 8);
                apre[p][1] = *(const float4*)(Aptr + k0 + p * 8 + 4);
            }
            #pragma unroll
            for (int p = 0; p < 4; ++p) cp16(aB[p] + k0, &Bbuf[(s + 1) & 1][bofs[p]]);
        }

        const unsigned short* La = Abuf[s & 1];
        const unsigned short* Lb = Bbuf[s & 1];
        #pragma unroll
        for (int kk = 0; kk < 4; ++kk) {
            const int kg = kk * 4 + (l >> 4);
            const int ks = (kg ^ (l & 15)) * 8;
            bf16x8 a0 = *(const bf16x8*)&La[rowA0 + ks];
            bf16x8 a1 = *(const bf16x8*)&La[rowA1 + ks];
            bf16x8 b0 = *(const bf16x8*)&Lb[rowB0 + ks];
            bf16x8 b1 = *(const bf16x8*)&Lb[rowB1 + ks];
            acc[0][0] = __builtin_amdgcn_mfma_f32_16x16x32_bf16(a0, b0, acc[0][0], 0, 0, 0);
            acc[0][1] = __builtin_amdgcn_mfma_f32_16x16x32_bf16(a0, b1, acc[0][1], 0, 0, 0);
            acc[1][0] = __builtin_amdgcn_mfma_f32_16x16x32_bf16(a1, b0, acc[1][0], 0, 0, 0);
            acc[1][1] = __builtin_amdgcn_mfma_f32_16x16x32_bf16(a1, b1, acc[1][1], 0, 0, 0);
        }
        __syncthreads();   // all reads of buffers (s) done before A(s+1) stores
    }

    // epilogue: D layout col = l&15, row = (l>>4)*4 + reg  ->  M2h[b][n][k] fp16
    const int col = l & 15;
    #pragma unroll
    for (int nt = 0; nt < 2; ++nt) {
        #pragma unroll
        for (int jt = 0; jt < 2; ++jt) {
            const int jc = j0 + ((w >> 1) & 1) * 32 + jt * 16 + col;
            const int b = jc >> 4;
            const int k = jc & 15;
            __half* base = M2h + (size_t)b * (NB * KD) + k;
            #pragma unroll
            for (int r = 0; r < 4; ++r) {
                const int n = n0 + (w & 1) * 32 + nt * 16 + (l >> 4) * 4 + r;
                base[n * KD] = __float2half(acc[nt][jt][r]);
            }
        }
    }
}

// ---- kernel 3: pairwise (unchanged from R3) ----
union U8 { float4 f4[2]; h2 h[8]; };

__global__ __launch_bounds__(256) void k_pairwise(const __half* __restrict__ M2h,
                                                  float* __restrict__ out) {
    __shared__ __half rows[128 * KD];   // 4 KB
    __shared__ float part[256 * 4];     // 4 KB
    const int b = blockIdx.x;
    const int mh = blockIdx.y;
    const int t = threadIdx.x;
    const int qg = t & 63, ms = t >> 6;
    const __half* Mb = M2h + (size_t)b * (NB * KD);

    ((float4*)rows)[t] = ((const float4*)(Mb + mh * 128 * KD))[t];

    U8 q[4];
    #pragma unroll
    for (int r = 0; r < 4; ++r) {
        const __half* qp = Mb + (qg * 4 + r) * KD;
        q[r].f4[0] = *(const float4*)(qp);
        q[r].f4[1] = *(const float4*)(qp + 8);
    }
    __syncthreads();

    const h2 one = {(_Float16)1.0f, (_Float16)1.0f};
    float e[4] = {0.f, 0.f, 0.f, 0.f};

    #pragma unroll 2
    for (int m = 0; m < 32; ++m) {
        U8 p;
        const __half* rp = rows + (ms * 32 + m) * KD;
        p.f4[0] = *(const float4*)(rp);
        p.f4[1] = *(const float4*)(rp + 8);
        #pragma unroll
        for (int r = 0; r < 4; ++r) {
            float l0 = 0.f, l1 = 0.f;
            #pragma unroll
            for (int i = 0; i < 8; i += 2) {
                h2 d0 = q[r].h[i] - p.h[i];
                h2 d1 = q[r].h[i + 1] - p.h[i + 1];
                unsigned u0 = (*(unsigned*)&d0) & 0x7FFF7FFFu;
                unsigned u1 = (*(unsigned*)&d1) & 0x7FFF7FFFu;
                l0 = __builtin_amdgcn_fdot2(*(h2*)&u0, one, l0, false);
                l1 = __builtin_amdgcn_fdot2(*(h2*)&u1, one, l1, false);
            }
            e[r] += __expf(-(l0 + l1));
        }
    }

    #pragma unroll
    for (int r = 0; r < 4; ++r)
        part[(qg * 4 + r) * 4 + ms] = e[r];
    __syncthreads();

    float4 p4 = ((const float4*)part)[t];
    atomicAdd(&out[(size_t)t * OUT_F + IN_F + b], p4.x + p4.y + p4.z + p4.w);
}

extern "C" void kernel_launch(void* const* d_in, const int* in_sizes, int n_in,
                              void* d_out, int out_size, void* d_ws, size_t ws_size,
                              hipStream_t stream) {
    const float* x = (const float*)d_in[0];   // (256, 1024)
    const float* T = (const float*)d_in[1];   // (1024, 4096)
    float* out = (float*)d_out;               // (256, 1280)

    char* ws = (char*)d_ws;
    unsigned short* Tt = (unsigned short*)ws;                 // 8 MB
    __half* M2h        = (__half*)(ws + (1u << 23));          // 2 MB

    k_prep<<<dim3(4352), dim3(256), 0, stream>>>(x, T, out, Tt);
    k_gemm<<<dim3(64, 4), dim3(256), 0, stream>>>(x, Tt, M2h);
    k_pairwise<<<dim3(256, 2), dim3(256), 0, stream>>>(M2h, out);
}

// Round 5
// 96.267 us; speedup vs baseline: 1.0787x; 1.0787x over previous
//
#include <hip/hip_runtime.h>
#include <hip/hip_fp16.h>
#include <hip/hip_bf16.h>

#define NB 256
#define IN_F 1024
#define BEX 256
#define KD 16
#define NJ 4096
#define OUT_F 1280

typedef short bf16x8 __attribute__((ext_vector_type(8)));
typedef float f32x4 __attribute__((ext_vector_type(4)));
typedef _Float16 h2 __attribute__((ext_vector_type(2)));

__device__ inline unsigned short f2bf(float f) {
    __hip_bfloat16 h = __float2bfloat16(f);
    return *reinterpret_cast<unsigned short*>(&h);
}

__device__ inline void cp16(const void* g, void* l) {
    __builtin_amdgcn_global_load_lds((const __attribute__((address_space(1))) void*)g,
                                     (__attribute__((address_space(3))) void*)l, 16, 0, 0);
}

// ---- kernel 1: prep = transpose/convert T  +  copy x / bf16(x) / out-init ----
// blocks [0, 4096): transpose 32x32 tile of T (1024x4096 f32) -> Tt (4096x1024 bf16)
// blocks [4096, 4352): row r = bid-4096: out[r,:1024]=x[r], x_bf[r]=bf16(x[r]), out[r,1024:]=-1
__global__ __launch_bounds__(256) void k_prep(const float* __restrict__ x,
                                              const float* __restrict__ T,
                                              float* __restrict__ out,
                                              unsigned short* __restrict__ x_bf,
                                              unsigned short* __restrict__ Tt) {
    const int bid = blockIdx.x;
    const int t = threadIdx.x;
    if (bid < 4096) {
        __shared__ float tile[32][33];
        const int j0 = (bid & 127) * 32;
        const int i0 = (bid >> 7) * 32;
        {
            const int r = t >> 3, cg = (t & 7) << 2;
            float4 v = *(const float4*)(T + (size_t)(i0 + r) * NJ + j0 + cg);
            tile[r][cg + 0] = v.x; tile[r][cg + 1] = v.y;
            tile[r][cg + 2] = v.z; tile[r][cg + 3] = v.w;
        }
        __syncthreads();
        const int jr = t >> 3, ig = (t & 7) << 2;
        ushort4 o;
        o.x = f2bf(tile[ig + 0][jr]);
        o.y = f2bf(tile[ig + 1][jr]);
        o.z = f2bf(tile[ig + 2][jr]);
        o.w = f2bf(tile[ig + 3][jr]);
        *(ushort4*)(Tt + (size_t)(j0 + jr) * IN_F + i0 + ig) = o;
    } else {
        const int r = bid - 4096;
        float4 v = *(const float4*)(x + (size_t)r * IN_F + t * 4);
        *(float4*)(out + (size_t)r * OUT_F + t * 4) = v;
        ushort4 o;
        o.x = f2bf(v.x); o.y = f2bf(v.y); o.z = f2bf(v.z); o.w = f2bf(v.w);
        *(ushort4*)(x_bf + (size_t)r * IN_F + t * 4) = o;
        if (t < 64)
            *(float4*)(out + (size_t)r * OUT_F + IN_F + t * 4) =
                make_float4(-1.f, -1.f, -1.f, -1.f);
    }
}

// ---- kernel 2: bf16 MFMA GEMM: M2h[b][n][k] fp16 ----
// 64x64 tile per block, 4 waves each 32x32 (2x2 MFMA tiles), BK=128, double-buffered DMA.
// LDS swizzle: element (row, kg, e) at row*128 + (kg ^ (row&15))*8 + e
__global__ __launch_bounds__(256) void k_gemm(const unsigned short* __restrict__ A,   // [256][1024]
                                              const unsigned short* __restrict__ B,   // [4096][1024]
                                              __half* __restrict__ M2h) {
    __shared__ unsigned short lds[4][64 * 128];   // 64 KB
    const int t = threadIdx.x;
    const int w = t >> 6, l = t & 63;
    const int n0 = blockIdx.y * 64;
    const int j0 = blockIdx.x * 64;

    const unsigned short* aA[4];
    const unsigned short* aB[4];
    int lofs[4];
    #pragma unroll
    for (int p = 0; p < 4; ++p) {
        int s = t + p * 256;
        int r = s >> 4;
        int kg = (s & 15) ^ (r & 15);
        aA[p] = A + (size_t)(n0 + r) * IN_F + kg * 8;
        aB[p] = B + (size_t)(j0 + r) * IN_F + kg * 8;
        lofs[p] = s * 8;
    }

    f32x4 acc[2][2];
    #pragma unroll
    for (int i = 0; i < 2; ++i)
        #pragma unroll
        for (int j = 0; j < 2; ++j)
            acc[i][j] = (f32x4){0.f, 0.f, 0.f, 0.f};

    #pragma unroll
    for (int p = 0; p < 4; ++p) cp16(aA[p], &lds[0][lofs[p]]);
    #pragma unroll
    for (int p = 0; p < 4; ++p) cp16(aB[p], &lds[1][lofs[p]]);

    const int rowA0 = ((w & 1) * 32 + (l & 15)) * 128;
    const int rowA1 = rowA0 + 16 * 128;
    const int rowB0 = (((w >> 1) & 1) * 32 + (l & 15)) * 128;
    const int rowB1 = rowB0 + 16 * 128;

    for (int s = 0; s < 8; ++s) {
        __syncthreads();
        if (s < 7) {
            const int k0 = (s + 1) * 128;
            const int bsel = ((s + 1) & 1) * 2;
            #pragma unroll
            for (int p = 0; p < 4; ++p) cp16(aA[p] + k0, &lds[bsel + 0][lofs[p]]);
            #pragma unroll
            for (int p = 0; p < 4; ++p) cp16(aB[p] + k0, &lds[bsel + 1][lofs[p]]);
        }
        const unsigned short* La = lds[(s & 1) * 2 + 0];
        const unsigned short* Lb = lds[(s & 1) * 2 + 1];
        #pragma unroll
        for (int kk = 0; kk < 4; ++kk) {
            const int kg = kk * 4 + (l >> 4);
            const int ks = (kg ^ (l & 15)) * 8;
            bf16x8 a0 = *(const bf16x8*)&La[rowA0 + ks];
            bf16x8 a1 = *(const bf16x8*)&La[rowA1 + ks];
            bf16x8 b0 = *(const bf16x8*)&Lb[rowB0 + ks];
            bf16x8 b1 = *(const bf16x8*)&Lb[rowB1 + ks];
            acc[0][0] = __builtin_amdgcn_mfma_f32_16x16x32_bf16(a0, b0, acc[0][0], 0, 0, 0);
            acc[0][1] = __builtin_amdgcn_mfma_f32_16x16x32_bf16(a0, b1, acc[0][1], 0, 0, 0);
            acc[1][0] = __builtin_amdgcn_mfma_f32_16x16x32_bf16(a1, b0, acc[1][0], 0, 0, 0);
            acc[1][1] = __builtin_amdgcn_mfma_f32_16x16x32_bf16(a1, b1, acc[1][1], 0, 0, 0);
        }
    }

    const int col = l & 15;
    #pragma unroll
    for (int nt = 0; nt < 2; ++nt) {
        #pragma unroll
        for (int jt = 0; jt < 2; ++jt) {
            const int jc = j0 + ((w >> 1) & 1) * 32 + jt * 16 + col;
            const int b = jc >> 4;
            const int k = jc & 15;
            __half* base = M2h + (size_t)b * (NB * KD) + k;
            #pragma unroll
            for (int r = 0; r < 4; ++r) {
                const int n = n0 + (w & 1) * 32 + nt * 16 + (l >> 4) * 4 + r;
                base[n * KD] = __float2half(acc[nt][jt][r]);
            }
        }
    }
}

// ---- kernel 3: pairwise ----
// grid (256 b, 2 mhalf); block 256. Stage 128 m-rows (4 KB). Thread t: qg=t&63 owns
// q-rows qg*4..+3 (regs), ms=t>>6 covers m in [ms*32, +32). fdot2 L1 accumulate,
// in-block reduction over ms, one atomicAdd per (q,b) per block.
union U8 { float4 f4[2]; h2 h[8]; };

__global__ __launch_bounds__(256) void k_pairwise(const __half* __restrict__ M2h,
                                                  float* __restrict__ out) {
    __shared__ __half rows[128 * KD];   // 4 KB
    __shared__ float part[256 * 4];     // 4 KB
    const int b = blockIdx.x;
    const int mh = blockIdx.y;
    const int t = threadIdx.x;
    const int qg = t & 63, ms = t >> 6;
    const __half* Mb = M2h + (size_t)b * (NB * KD);

    ((float4*)rows)[t] = ((const float4*)(Mb + mh * 128 * KD))[t];

    U8 q[4];
    #pragma unroll
    for (int r = 0; r < 4; ++r) {
        const __half* qp = Mb + (qg * 4 + r) * KD;
        q[r].f4[0] = *(const float4*)(qp);
        q[r].f4[1] = *(const float4*)(qp + 8);
    }
    __syncthreads();

    const h2 one = {(_Float16)1.0f, (_Float16)1.0f};
    float e[4] = {0.f, 0.f, 0.f, 0.f};

    #pragma unroll 2
    for (int m = 0; m < 32; ++m) {
        U8 p;
        const __half* rp = rows + (ms * 32 + m) * KD;
        p.f4[0] = *(const float4*)(rp);
        p.f4[1] = *(const float4*)(rp + 8);
        #pragma unroll
        for (int r = 0; r < 4; ++r) {
            float l0 = 0.f, l1 = 0.f;
            #pragma unroll
            for (int i = 0; i < 8; i += 2) {
                h2 d0 = q[r].h[i] - p.h[i];
                h2 d1 = q[r].h[i + 1] - p.h[i + 1];
                unsigned u0 = (*(unsigned*)&d0) & 0x7FFF7FFFu;
                unsigned u1 = (*(unsigned*)&d1) & 0x7FFF7FFFu;
                l0 = __builtin_amdgcn_fdot2(*(h2*)&u0, one, l0, false);
                l1 = __builtin_amdgcn_fdot2(*(h2*)&u1, one, l1, false);
            }
            e[r] += __expf(-(l0 + l1));
        }
    }

    #pragma unroll
    for (int r = 0; r < 4; ++r)
        part[(qg * 4 + r) * 4 + ms] = e[r];
    __syncthreads();

    float4 p4 = ((const float4*)part)[t];
    atomicAdd(&out[(size_t)t * OUT_F + IN_F + b], p4.x + p4.y + p4.z + p4.w);
}

extern "C" void kernel_launch(void* const* d_in, const int* in_sizes, int n_in,
                              void* d_out, int out_size, void* d_ws, size_t ws_size,
                              hipStream_t stream) {
    const float* x = (const float*)d_in[0];   // (256, 1024)
    const float* T = (const float*)d_in[1];   // (1024, 4096)
    float* out = (float*)d_out;               // (256, 1280)

    char* ws = (char*)d_ws;
    unsigned short* x_bf = (unsigned short*)ws;                        // 512 KB
    unsigned short* Tt   = (unsigned short*)(ws + (1u << 19));         // 8 MB
    __half* M2h          = (__half*)(ws + (1u << 19) + (1u << 23));    // 2 MB

    k_prep<<<dim3(4352), dim3(256), 0, stream>>>(x, T, out, x_bf, Tt);
    k_gemm<<<dim3(64, 4), dim3(256), 0, stream>>>(x_bf, Tt, M2h);
    k_pairwise<<<dim3(256, 2), dim3(256), 0, stream>>>(M2h, out);
}